// Round 13
// baseline (339.793 us; speedup 1.0000x reference)
//
#include <hip/hip_runtime.h>

#define INFV 1e8f
#define LN2F 0.69314718055994530942f
#define L2EF 1.44269504088896340736f

constexpr int NC = 512;   // DP columns
constexpr int NR = 512;   // DP rows
constexpr int RC = 72;    // ring columns (9 panels of 8); 72*512*4 = 147456 B
constexpr int NSW = 576;  // steps (t=575 computes nothing; keeps 8-phase cadence)

// ONE wave per batch (no cross-wave machinery at all: no mailbox, no
// handshake, no atomics, no barriers). Lane l owns rows 8l..8l+7.
// Ring: [col%72][512] floats, in-place e^{-D} -> R (R10-proven semantics).
// Per-step LDS: 2x ds_read_b128 (next col's e^{-D}) + 2x ds_write_b128 (R).
// Cross-lane handoff: DPP wave_shr:1 (pure VALU). P-domain cells with
// private scale E (renorm every 8 steps), log-domain lane interface
// (scale-free) -- the R8/R10/R12 proven math core, 8 cells per step.
static __device__ __forceinline__ float wave_shr1(float v, float old) {
    // lanes 1..63 <- lane-1's v; lane 0 keeps `old` (bound_ctrl=false)
    return __int_as_float(__builtin_amdgcn_update_dpp(
        __float_as_int(old), __float_as_int(v), 0x138, 0xF, 0xF, false));
}

__global__ __launch_bounds__(64, 1) void sdtw8(const float* __restrict__ D,
                                               float* __restrict__ O) {
    __shared__ float ring[RC * NR];  // 147456 B

    const int l = threadIdx.x;  // 0..63
    const int b = blockIdx.x;
    const float* __restrict__ Dg = D + (size_t)b * NR * NC;
    float* __restrict__ Og = O + (size_t)b * NR * NC;
    float* __restrict__ rg = ring;

    // panel helpers (R8-proven enumeration): 512 rows x 8 cols = 1024 float4;
    // f = k*64 + l -> y = 32k + (l>>1), q = l&1 (lane pairs share a row ->
    // coalesced global, 2-way LDS bank aliasing = free).
    float4 st[16];  // staging for the next D panel
    auto panel_load = [&](int p) {
#pragma unroll
        for (int k = 0; k < 16; ++k) {
            const int f = k * 64 + l, y = f >> 1, q = f & 1;
            st[k] = *(const float4*)(Dg + (size_t)y * NC + p * 8 + q * 4);
        }
    };
    auto panel_write = [&](int p) {  // st -> ring, storing e^{-D}
        const int sb = (p * 8) % RC;  // in {0,8,...,64}; sb+7 <= 71, no wrap
#pragma unroll
        for (int k = 0; k < 16; ++k) {
            const int f = k * 64 + l, y = f >> 1, q = f & 1;
#pragma unroll
            for (int j = 0; j < 4; ++j)
                rg[(sb + q * 4 + j) * NR + y] = __expf(-((const float*)&st[k])[j]);
        }
    };
    auto panel_flush = [&](int p) {  // ring (R values) -> global
        const int sb = (p * 8) % RC;
#pragma unroll
        for (int k = 0; k < 16; ++k) {
            const int f = k * 64 + l, y = f >> 1, q = f & 1;
            float4 v;
#pragma unroll
            for (int j = 0; j < 4; ++j)
                ((float*)&v)[j] = rg[(sb + q * 4 + j) * NR + y];
            *(float4*)(Og + (size_t)y * NC + p * 8 + q * 4) = v;
        }
    };

    // prologue: panels 0..8 fill the ring (72 cols); stage panel 9
    for (int p = 0; p < 9; ++p) { panel_load(p); panel_write(p); }
    panel_load(9);

    const int y0 = 8 * l;  // this lane's rows y0..y0+7
    float prevP[8];        // P[row, u-1] at scale E; col-0 boundary = 0
#pragma unroll
    for (int r = 0; r < 8; ++r) prevP[r] = 0.0f;
    float E = 0.0f;                       // private scale: stored = true * 2^E
    float bp_r = (l == 0) ? 0.0f : INFV;  // log R[y0-1, u-1]; lane0: R[0,0]=0
    float r_out = INFV;                   // log R[y0+7, u] for lane l+1
    float vab_prev = 0.0f;                // cached P(R[y0-1, u-1])

    // pd = e^{-D[rows, col clamp(u)]}, prefetched one step early
    float pd[8], pdn[8];
    {
        const float4 a = *(const float4*)&rg[y0];      // col 0 (slot 0)
        const float4 b4 = *(const float4*)&rg[y0 + 4];
#pragma unroll
        for (int j = 0; j < 4; ++j) { pd[j] = ((const float*)&a)[j]; pd[4 + j] = ((const float*)&b4)[j]; }
    }
    int uc_cur = 0, slot_cur = 0;  // tracker: col/slot of current pd

    for (int t = 0; t < NSW; ++t) {
        const int u = t - l;
        const bool valid = (u >= 0) && (u < NC);

        const float up_r = wave_shr1(r_out, INFV);  // log R[y0-1, u]

        // write target = col u's slot (tracker pre-advance, R12-proven)
        const int base_wr = slot_cur * NR;
        // advance tracker to col clamp(u+1); prefetch its e^{-D}
        const int uc = min(max(u + 1, 0), NC - 1);
        if (uc > uc_cur) {
            uc_cur = uc;
            slot_cur = (slot_cur + 1 == RC) ? 0 : slot_cur + 1;
        }
        {
            const float4 a = *(const float4*)&rg[slot_cur * NR + y0];
            const float4 b4 = *(const float4*)&rg[slot_cur * NR + y0 + 4];
#pragma unroll
            for (int j = 0; j < 4; ++j) { pdn[j] = ((const float*)&a)[j]; pdn[4 + j] = ((const float*)&b4)[j]; }
        }

        const float dab_log = bp_r;  // log R[y0-1, u-1]
        bp_r = up_r;

        if (valid) {
            float dab;
            if (u == 0) {  // cold start: adopt scale, pin boundary ~2^10
                E = (l == 0) ? 0.0f : floorf(up_r * L2EF) + 10.0f;
                dab = __expf(fmaf(E, LN2F, -dab_log));
            } else {
                dab = vab_prev;
            }
            const float vab = __expf(fmaf(E, LN2F, -up_r));  // chain exp
            float o[8];
            float diag = dab, vert = vab;
#pragma unroll
            for (int r = 0; r < 8; ++r) {
                const float ss = (diag + vert) + prevP[r];  // chain: 2 add
                const float cur = pd[r] * ss;               // chain: 1 mul
                o[r] = fmaf(E, LN2F, -__logf(cur));         // off-chain (exc. r=7)
                diag = prevP[r];
                vert = cur;
                prevP[r] = cur;
            }
            *(float4*)&rg[base_wr + y0] = make_float4(o[0], o[1], o[2], o[3]);
            *(float4*)&rg[base_wr + y0 + 4] = make_float4(o[4], o[5], o[6], o[7]);
            vab_prev = vab;
            r_out = o[7];
        }

        // renorm every 8 steps: pin stored prevP[0] to ~2^10; rescale all
        // P-state (incl. vab_prev). Log-domain r_out is immune to timing.
        if ((t & 7) == 7) {
            const int ex = (int)((__float_as_uint(prevP[0]) >> 23) & 0xffu);
            if (ex != 0) {
                const int sh = 137 - ex;
                const float f = __uint_as_float((unsigned)(sh + 127) << 23);
                E += (float)sh;
#pragma unroll
                for (int r = 0; r < 8; ++r) prevP[r] *= f;
                vab_prev *= f;
            }
        }
#pragma unroll
        for (int r = 0; r < 8; ++r) pd[r] = pdn[r];

        // panel event every 8 steps: t = 8m+6, m = 8..71. Panel m-8's last
        // col (8m-57) was written by lane 63 THIS step. panel_write targets
        // cols 8m+8.. ; max prefetched col this step = u+1 = 8m+7 -> no race.
        if ((t & 7) == 6 && t >= 70) {
            const int m = t >> 3;
            panel_flush(m - 8);
            const int pr = m + 1;
            if (pr < 64) {
                panel_write(pr);
                if (pr + 1 < 64) panel_load(pr + 1);
            }
        }
    }
}

extern "C" void kernel_launch(void* const* d_in, const int* in_sizes, int n_in,
                              void* d_out, int out_size, void* d_ws, size_t ws_size,
                              hipStream_t stream) {
    const float* D = (const float*)d_in[0];
    float* out = (float*)d_out;
    const int B = in_sizes[0] / (NR * NC);
    sdtw8<<<B, 64, 0, stream>>>(D, out);
}

// Round 14
// 252.756 us; speedup vs baseline: 1.3444x; 1.3444x over previous
//
#include <hip/hip_runtime.h>

#define INFV 1e8f
#define LN2F 0.69314718055994530942f
#define L2EF 1.44269504088896340736f

constexpr int NC = 512;   // DP columns
constexpr int RW = 128;   // rows per wave
constexpr int NW = 4;     // waves per block
constexpr int RC = 72;    // ring columns per wave (9 panels of 8)
constexpr int GOFF = 11;  // wave offset in groups (= 88 steps, R12-proven)
constexpr int NGRP = 105; // ceil((575 + 3*88) / 8)

// R12 structure (4 waves/batch, 2 rows/lane, private in-place LDS ring, DPP
// handoff, P-domain cells, flag handshake) restructured into 8-step GROUPS
// with all LDS traffic at group boundaries:
//   group start: 2x b128 mailbox read (8 cols) + 8x b64 pd pre-read
//   8 phases:    pure VALU/DPP/trans compute, zero LDS
//   group end:   8x b64 ring writes, 2x b128 mailbox write (carry-aligned),
//                pflag publish, panel event (flush/write/load)
// Handshake: consumer group h needs producer cols <= tb+7 -> need = tb+8;
// producer publishes cnt = tb-56 after group h (cols 0..tb-57 committed,
// last col carried one group). Lockstep slack = 2 groups. No flow control
// needed (full-width mailbox). Spin guard 2^24 -> fails absmax, not hangs.
static __device__ __forceinline__ float wave_shr1(float v, float old) {
    // lanes 1..63 <- lane-1's v; lane 0 keeps `old` (bound_ctrl=false)
    return __int_as_float(__builtin_amdgcn_update_dpp(
        __float_as_int(old), __float_as_int(v), 0x138, 0xF, 0xF, false));
}

__global__ __launch_bounds__(256, 1) void sdtw9(const float* __restrict__ D,
                                                float* __restrict__ O) {
    __shared__ __align__(16) float ring[NW * RC * RW];  // 147456 B
    __shared__ __align__(16) float mbox[3 * NC];        // 6144 B
    __shared__ int pflag[4];

    const int tid = threadIdx.x;
    const int w = tid >> 6, l = tid & 63;
    const int b = blockIdx.x;

    if (tid < 4) pflag[tid] = 0;
    __syncthreads();  // once; no barriers in the loop

    const float* __restrict__ Dg = D + (size_t)b * NC * 512 + (size_t)w * RW * NC;
    float* __restrict__ Og = O + (size_t)b * NC * 512 + (size_t)w * RW * NC;
    float* __restrict__ rg = ring + w * RC * RW;

    // panel helpers (R12-proven): 128 rows x 8 cols; f = k*64+l, y=f>>1, q=f&1
    float4 st[4];
    auto panel_load = [&](int p) {
#pragma unroll
        for (int k = 0; k < 4; ++k) {
            const int f = k * 64 + l, y = f >> 1, q = f & 1;
            st[k] = *(const float4*)(Dg + (size_t)y * NC + p * 8 + q * 4);
        }
    };
    auto panel_write = [&](int p) {  // stores e^{-D}
#pragma unroll
        for (int k = 0; k < 4; ++k) {
            const int f = k * 64 + l, y = f >> 1, q = f & 1;
            const int ub = p * 8 + q * 4;
#pragma unroll
            for (int j = 0; j < 4; ++j) {
                const int u = ub + j;
                rg[(u % RC) * RW + (y ^ (u & 30))] = __expf(-((const float*)&st[k])[j]);
            }
        }
    };
    auto panel_flush = [&](int p) {  // ring (R values) -> global
#pragma unroll
        for (int k = 0; k < 4; ++k) {
            const int f = k * 64 + l, y = f >> 1, q = f & 1;
            const int ub = p * 8 + q * 4;
            float4 v;
#pragma unroll
            for (int j = 0; j < 4; ++j) {
                const int u = ub + j;
                ((float*)&v)[j] = rg[(u % RC) * RW + (y ^ (u & 30))];
            }
            *(float4*)(Og + (size_t)y * NC + ub) = v;
        }
    };

    for (int p = 0; p < 9; ++p) { panel_load(p); panel_write(p); }
    panel_load(9);

    const int y0 = 2 * l;
    float prevP0 = 0.0f, prevP1 = 0.0f;  // P[row, u-1] at scale E
    float h01 = 0.0f;                    // prevP0 + prevP1
    float E = 0.0f;                      // private scale
    float bp_r = (w == 0 && l == 0) ? 0.0f : INFV;  // log R[above, u-1]
    float r_out = INFV;                  // log R[y0+1, u]
    float vab_prev = 0.0f;               // cached P(R[above, u-1])
    float carry = INFV;                  // lane63 o1 carried one group (align)

    for (int g = 0; g < NGRP; ++g) {
        const int h = g - GOFF * w;      // wave-local group index
        if (h < 0 || h > 71) continue;   // wave-uniform; no barriers inside
        const int tb = 8 * h;            // local t of phase 0

        // ---- group start: mailbox batch read (consumer) ----
        float mbgrp[8];
        if (w > 0 && h <= 63) {
            const int need = tb + 8;  // cols tb..tb+7 required
            int guard = 0;
            while (__hip_atomic_load(&pflag[w - 1], __ATOMIC_ACQUIRE,
                                     __HIP_MEMORY_SCOPE_WORKGROUP) < need &&
                   ++guard < (1 << 24)) {}
            const float4 m0 = *(const float4*)&mbox[(w - 1) * NC + tb];
            const float4 m1 = *(const float4*)&mbox[(w - 1) * NC + tb + 4];
            mbgrp[0] = m0.x; mbgrp[1] = m0.y; mbgrp[2] = m0.z; mbgrp[3] = m0.w;
            mbgrp[4] = m1.x; mbgrp[5] = m1.y; mbgrp[6] = m1.z; mbgrp[7] = m1.w;
        } else {
#pragma unroll
            for (int j = 0; j < 8; ++j) mbgrp[j] = INFV;
        }

        // ---- group start: pd pre-reads (8x b64, one lgkm region) ----
        int ad[8];
        float2 pdv[8];
#pragma unroll
        for (int ph = 0; ph < 8; ++ph) {
            const int c = tb + ph - l;
            const int cs = min(max(c, 0), NC - 1);
            ad[ph] = (cs % RC) * RW + (y0 ^ (cs & 30));
            pdv[ph] = *(const float2*)&rg[ad[ph]];
        }

        // ---- 8 phases: pure compute, zero LDS ----
        float2 obuf[8];
        float mbuf[8];
#pragma unroll
        for (int ph = 0; ph < 8; ++ph) {
            const int u = tb + ph - l;
            const bool valid = (u >= 0) && (u < NC);
            const float bnd = (w == 0) ? INFV : mbgrp[ph];
            const float up_r = wave_shr1(r_out, bnd);  // log R[y0-1, u]
            const float dab_log = bp_r;                // log R[y0-1, u-1]
            bp_r = up_r;
            if (valid) {
                float dab;
                if (u == 0) {  // cold start: adopt scale, pin boundary ~2^10
                    E = (w == 0 && l == 0) ? 0.0f : floorf(up_r * L2EF) + 10.0f;
                    dab = __expf(fmaf(E, LN2F, -dab_log));
                } else {
                    dab = vab_prev;
                }
                const float vab = __expf(fmaf(E, LN2F, -up_r));  // chain exp
                const float s0 = (dab + vab) + prevP0;
                const float c0 = pdv[ph].x * s0;
                const float s1 = h01 + c0;
                const float c1 = pdv[ph].y * s1;
                const float o0 = fmaf(E, LN2F, -__logf(c0));
                const float o1 = fmaf(E, LN2F, -__logf(c1));
                obuf[ph] = make_float2(o0, o1);
                prevP0 = c0; prevP1 = c1; h01 = c0 + c1;
                vab_prev = vab;
                r_out = o1;
                mbuf[ph] = o1;
            }
            if (ph == 7) {  // renorm: pin stored prevP0 ~2^10
                const int ex = (int)((__float_as_uint(prevP0) >> 23) & 0xffu);
                if (ex != 0) {
                    const int sh = 137 - ex;
                    const float f = __uint_as_float((unsigned)(sh + 127) << 23);
                    E += (float)sh;
                    prevP0 *= f; prevP1 *= f; h01 *= f; vab_prev *= f;
                }
            }
        }

        // ---- group end: batched ring writes (R replaces e^{-D}) ----
#pragma unroll
        for (int ph = 0; ph < 8; ++ph) {
            const int u = tb + ph - l;
            if (u >= 0 && u < NC) *(float2*)&rg[ad[ph]] = obuf[ph];
        }

        // ---- group end: mailbox batch write + publish (producer) ----
        if (w < 3) {
            if (h >= 8 && l == 63) {  // cols tb-64..tb-57 (16B aligned)
                *(float4*)&mbox[w * NC + tb - 64] =
                    make_float4(carry, mbuf[0], mbuf[1], mbuf[2]);
                *(float4*)&mbox[w * NC + tb - 60] =
                    make_float4(mbuf[3], mbuf[4], mbuf[5], mbuf[6]);
            }
            carry = mbuf[7];
            if (h >= 8 && l == 0) {
                __hip_atomic_store(&pflag[w], tb - 56, __ATOMIC_RELEASE,
                                   __HIP_MEMORY_SCOPE_WORKGROUP);
            }
        }

        // ---- group end: panel event (private ring; R12-proven pipeline) ----
        if (h >= 8) {
            panel_flush(h - 8);  // cols tb-64..tb-57, completed this group
            if (h + 1 < 64) {
                panel_write(h + 1);              // st staged last group
                if (h + 2 < 64) panel_load(h + 2);
            }
        }
    }
}

extern "C" void kernel_launch(void* const* d_in, const int* in_sizes, int n_in,
                              void* d_out, int out_size, void* d_ws, size_t ws_size,
                              hipStream_t stream) {
    const float* D = (const float*)d_in[0];
    float* out = (float*)d_out;
    const int B = in_sizes[0] / (512 * 512);
    sdtw9<<<B, 256, 0, stream>>>(D, out);
}